// Round 8
// baseline (354.361 us; speedup 1.0000x reference)
//
#include <hip/hip_runtime.h>

// Problem geometry: NEW_SHAPE = (16,16,512,64) flat-indexed as
//   idx = rc*32768 + i*64 + j   with rc = col*16+row, i in [0,512), j in [0,64)
//   weight element: (rc, i>>3, j); slice s = i&7 (MSB-first => shift = 14 - 2*s)
#define NELEM  (16 * 16 * 512 * 64)   // 8,388,608
#define EIGHTH (NELEM / 8)            // 1,048,576  (bit 20 upward => rc += 32 per chunk)

// native clang vector type — accepted by __builtin_nontemporal_load
typedef float f32x4 __attribute__((ext_vector_type(4)));

// branchless select of one lane of an f32x4 by code c in {0,1,2,3}
__device__ __forceinline__ float sel4(f32x4 v, int c) {
    return (c & 1) ? ((c & 2) ? v.w : v.y)
                   : ((c & 2) ? v.z : v.x);
}

__global__ __launch_bounds__(256) void w2g_main_kernel(
    const float*  __restrict__ input,     // (16,16,64,64) fp32, 4 MB (reused 8x, stays cached)
    const f32x4*  __restrict__ meanG,     // (NELEM,4) fp32, single-use stream
    const f32x4*  __restrict__ sigG,      // (NELEM,4) fp32, single-use stream
    const float*  __restrict__ eps,       // (NELEM) fp32, single-use stream
    const unsigned char* __restrict__ mask8,
    const unsigned int*  __restrict__ maskw,
    float* __restrict__ out)              // 4*NELEM: [Gp*am][Gn*am][Gp*!am][Gn*!am]
{
    int tid = blockIdx.x * blockDim.x + threadIdx.x;   // [0, EIGHTH)

    // ---- inline mask-dtype detection (wave-uniform, first 64 words) -------
    // byte-bool mask -> some word > 1 and none == 0x3F800000; int32/float32
    // masks both reduce to (word != 0), so only byte-vs-word matters.
    unsigned int probe = maskw[threadIdx.x & 63];
    bool isF = (probe == 0x3F800000u);
    bool isB = (probe > 1u) && !isF;
    unsigned long long anyF = __ballot(isF);
    unsigned long long anyB = __ballot(isB);
    bool byteMode = (anyF == 0ull) && (anyB != 0ull);

    // ---- index decomposition shared by all 8 strided elements -------------
    // k*EIGHTH only touches bits >= 20, so j, i, shift are k-invariant.
    int j     = tid & 63;
    int i     = (tid >> 6) & 511;
    int rc0   = tid >> 15;                 // [0,32)
    int shift = 14 - 2 * (i & 7);          // MSB-first 2-bit slice
    int ibase = ((i >> 3) << 6) | j;       // weight offset within one rc plane

    // ---- phase 1: issue ALL loads into distinct registers (max MLP) -------
    f32x4 m4[8], s4[8];
    float e[8], w[8];
    unsigned int mk[8];

#pragma unroll
    for (int k = 0; k < 8; ++k) {
        int idx = tid + k * EIGHTH;
        m4[k] = __builtin_nontemporal_load(&meanG[idx]);
        s4[k] = __builtin_nontemporal_load(&sigG[idx]);
        e[k]  = __builtin_nontemporal_load(&eps[idx]);
        w[k]  = input[((rc0 + (k << 5)) << 12) | ibase];   // L2/L3-resident
    }
    if (byteMode) {
#pragma unroll
        for (int k = 0; k < 8; ++k) mk[k] = mask8[tid + k * EIGHTH];
    } else {
#pragma unroll
        for (int k = 0; k < 8; ++k) mk[k] = maskw[tid + k * EIGHTH];
    }

    // ---- phase 2: compute + store -----------------------------------------
#pragma unroll
    for (int k = 0; k < 8; ++k) {
        int idx = tid + k * EIGHTH;

        int wi = (int)w[k];                // exact: integers in [-32767, 32767]
        int p  = wi > 0 ?  wi : 0;
        int n  = wi > 0 ?  0  : -wi;
        int cp = (p >> shift) & 3;
        int cn = (n >> shift) & 3;

        float Gp = sel4(m4[k], cp) + e[k] * sel4(s4[k], cp);
        float Gn = sel4(m4[k], cn) + e[k] * sel4(s4[k], cn);
        bool  am = (mk[k] != 0u);

        __builtin_nontemporal_store(am ? Gp : 0.0f, &out[idx]);
        __builtin_nontemporal_store(am ? Gn : 0.0f, &out[NELEM + idx]);
        __builtin_nontemporal_store(am ? 0.0f : Gp, &out[2 * NELEM + idx]);
        __builtin_nontemporal_store(am ? 0.0f : Gn, &out[3 * NELEM + idx]);
    }
}

extern "C" void kernel_launch(void* const* d_in, const int* in_sizes, int n_in,
                              void* d_out, int out_size, void* d_ws, size_t ws_size,
                              hipStream_t stream) {
    const float*  input = (const float*) d_in[0];
    const f32x4*  meanG = (const f32x4*) d_in[1];
    const f32x4*  sigG  = (const f32x4*) d_in[2];
    const float*  eps   = (const float*) d_in[3];
    const void*   mask  = d_in[4];

    int threads = 256;
    int blocks  = EIGHTH / threads;        // 4096
    w2g_main_kernel<<<blocks, threads, 0, stream>>>(
        input, meanG, sigG, eps,
        (const unsigned char*)mask, (const unsigned int*)mask,
        (float*)d_out);
}